// Round 1
// baseline (1234.790 us; speedup 1.0000x reference)
//
#include <hip/hip_runtime.h>
#include <math.h>

#define NEG_INF -1e30f

constexpr int B = 4;
constexpr int H = 32;
constexpr int D = 128;
constexpr int S = 8192;
constexpr int NSPLIT = 16;
constexpr int SPLIT_LEN = S / NSPLIT;       // 512
constexpr int THREADS = 256;
constexpr int GROUPS = THREADS / 32;        // 8 row-groups of 32 lanes
constexpr int ITERS = SPLIT_LEN / GROUPS;   // 64

// Kernel 1: per (b,h,split) partial flash-decode: m, l, o[D] over a 512-pos chunk.
__global__ __launch_bounds__(THREADS) void attn_partial(
    const float* __restrict__ x,        // [B,1,H,D]
    const float* __restrict__ kv,       // [2,B,S,H,D]
    const int* __restrict__ pos_ptr,    // scalar current_pos (device)
    float* __restrict__ o_part,         // [B*H*NSPLIT, D]
    float* __restrict__ ml_part)        // [B*H*NSPLIT, 2] (m, l)
{
    const int blk   = blockIdx.x;
    const int split = blk % NSPLIT;
    const int bh    = blk / NSPLIT;
    const int b     = bh / H;
    const int h     = bh % H;
    const int pos   = *pos_ptr;
    const int s_base = split * SPLIT_LEN;
    const int slot  = bh * NSPLIT + split;

    const int t = threadIdx.x;
    const int g = t >> 5;    // row-group 0..7
    const int c = t & 31;    // lane within group

    __shared__ float sc[SPLIT_LEN];       // scores -> probs (2 KB)
    __shared__ float red[GROUPS][D];      // V-accum cross-group reduce (4 KB)
    __shared__ float wredm[4], wredl[4];

    if (s_base > pos) {                   // fully-masked chunk: no loads at all
        if (t == 0) { ml_part[slot * 2 + 0] = NEG_INF; ml_part[slot * 2 + 1] = 0.0f; }
        return;
    }

    // q fragment: this lane owns d = c*4 .. c*4+3
    const float4 qf = ((const float4*)(x + ((size_t)b * H + h) * D))[c];
    const float scale = 0.08838834764831845f;   // 1/sqrt(128)

    // K/V row base for (b, s, h): ((b*S+s)*H + h)*D
    const float*  kbase   = kv + (((size_t)b * S) * H + h) * (size_t)D;
    const float*  vbase   = kbase + (size_t)B * S * H * D;
    const size_t  rstride = (size_t)H * D;      // floats between consecutive s

    // ---- scores ----
    sc[t] = NEG_INF;
    sc[t + 256] = NEG_INF;
    __syncthreads();

    for (int it = 0; it < ITERS; ++it) {
        const int s_local = it * GROUPS + g;
        const int s = s_base + s_local;
        if (s > pos) break;               // monotone in it -> safe per-thread break
        const float4 kf = ((const float4*)(kbase + (size_t)s * rstride))[c];
        float d = qf.x * kf.x + qf.y * kf.y + qf.z * kf.z + qf.w * kf.w;
        d += __shfl_xor(d, 16);
        d += __shfl_xor(d, 8);
        d += __shfl_xor(d, 4);
        d += __shfl_xor(d, 2);
        d += __shfl_xor(d, 1);
        if (c == 0) sc[s_local] = d * scale;
    }
    __syncthreads();

    // ---- block max ----
    float m = fmaxf(sc[t], sc[t + 256]);
    #pragma unroll
    for (int off = 32; off >= 1; off >>= 1) m = fmaxf(m, __shfl_xor(m, off));
    if ((t & 63) == 0) wredm[t >> 6] = m;
    __syncthreads();
    m = fmaxf(fmaxf(wredm[0], wredm[1]), fmaxf(wredm[2], wredm[3]));

    // ---- probs + block sum ----
    const float p0 = __expf(sc[t] - m);         // masked scores -> exp(-1e30) == 0
    const float p1 = __expf(sc[t + 256] - m);
    sc[t] = p0;                                  // own slots only; no cross-thread hazard
    sc[t + 256] = p1;
    float l = p0 + p1;
    #pragma unroll
    for (int off = 32; off >= 1; off >>= 1) l += __shfl_xor(l, off);
    if ((t & 63) == 0) wredl[t >> 6] = l;
    __syncthreads();                             // covers sc prob-writes + wredl
    l = wredl[0] + wredl[1] + wredl[2] + wredl[3];

    // ---- o = P @ V (partial) ----
    float4 acc = {0.f, 0.f, 0.f, 0.f};
    for (int j = 0; j < ITERS; ++j) {
        const int s_local = j * GROUPS + g;
        const int s = s_base + s_local;
        if (s > pos) break;
        const float p = sc[s_local];             // LDS broadcast within group
        const float4 vf = ((const float4*)(vbase + (size_t)s * rstride))[c];
        acc.x += p * vf.x; acc.y += p * vf.y; acc.z += p * vf.z; acc.w += p * vf.w;
    }
    ((float4*)red[g])[c] = acc;
    __syncthreads();
    if (t < 32) {
        float4 o = {0.f, 0.f, 0.f, 0.f};
        #pragma unroll
        for (int gg = 0; gg < GROUPS; ++gg) {
            const float4 r = ((float4*)red[gg])[t];
            o.x += r.x; o.y += r.y; o.z += r.z; o.w += r.w;
        }
        ((float4*)(o_part + (size_t)slot * D))[t] = o;
    }
    if (t == 0) { ml_part[slot * 2 + 0] = m; ml_part[slot * 2 + 1] = l; }
}

// Kernel 2: merge NSPLIT partials per (b,h). Grid = B*H, block = D threads.
__global__ __launch_bounds__(D) void attn_reduce(
    const float* __restrict__ o_part,   // [B*H*NSPLIT, D]
    const float* __restrict__ ml_part,  // [B*H*NSPLIT, 2]
    float* __restrict__ out)            // [B,1,H,D] -> [bh*D + d]
{
    const int bh = blockIdx.x;
    const int t  = threadIdx.x;         // d

    float M = NEG_INF;
    #pragma unroll
    for (int i = 0; i < NSPLIT; ++i)
        M = fmaxf(M, ml_part[(bh * NSPLIT + i) * 2 + 0]);

    float w[NSPLIT];
    float L = 0.f;
    #pragma unroll
    for (int i = 0; i < NSPLIT; ++i) {
        const float mi = ml_part[(bh * NSPLIT + i) * 2 + 0];
        const float li = ml_part[(bh * NSPLIT + i) * 2 + 1];
        const float wi = (li > 0.f) ? __expf(mi - M) : 0.f;
        w[i] = wi;
        L += li * wi;
    }

    float o = 0.f;
    #pragma unroll
    for (int i = 0; i < NSPLIT; ++i) {
        if (w[i] != 0.f)                // uniform branch: skip dead splits (poisoned ws)
            o += w[i] * o_part[(size_t)(bh * NSPLIT + i) * D + t];
    }
    out[(size_t)bh * D + t] = o / L;
}

extern "C" void kernel_launch(void* const* d_in, const int* in_sizes, int n_in,
                              void* d_out, int out_size, void* d_ws, size_t ws_size,
                              hipStream_t stream) {
    const float* x   = (const float*)d_in[0];
    const float* kv  = (const float*)d_in[1];
    const int*   pos = (const int*)d_in[2];
    float* out = (float*)d_out;

    float* o_part  = (float*)d_ws;                       // B*H*NSPLIT*D floats = 1 MB
    float* ml_part = o_part + (size_t)B * H * NSPLIT * D; // + B*H*NSPLIT*2 floats

    attn_partial<<<B * H * NSPLIT, THREADS, 0, stream>>>(x, kv, pos, o_part, ml_part);
    attn_reduce<<<B * H, D, 0, stream>>>(o_part, ml_part, out);
}